// Round 8
// baseline (266.584 us; speedup 1.0000x reference)
//
#include <hip/hip_runtime.h>

#define BN_EPS 1e-3f

using bfrag  = __attribute__((ext_vector_type(8))) short;  // 8 bf16 (4 VGPRs)
using f32x4v = __attribute__((ext_vector_type(4))) float;

__device__ __forceinline__ unsigned short f2bf(float f) {
    union { float f; unsigned u; } v; v.f = f;
    unsigned r = v.u + 0x7FFFu + ((v.u >> 16) & 1u);   // RNE
    return (unsigned short)(r >> 16);
}

// ---------------------------------------------------------------------------
// One prep kernel, thread ranges:
//  A: vf [N,16] fp32 -> xb0 [(N+1),16] bf16 (row N = zeros)
//  W: W0/W1 [27,16,16] -> Wb0/Wb1 MFMA B-frag order (14 K-steps)
//  F: Wf [16,128] -> Wfb B-frag order (8 col-tiles, K=16 padded to 32)
//  H: hidx[seg[r]] = r            (h contributor per slot; injective)
//  T: t2s[seg[N+r]] = r for run leaders (seg[N:2N] non-decreasing)
// Slots never written keep the 0xAA poison -> validity check in consumer.
// ---------------------------------------------------------------------------
__global__ __launch_bounds__(256)
void prep_kernel(const float* __restrict__ vf,
                 const float* __restrict__ W0, const float* __restrict__ W1,
                 const float* __restrict__ Wf, const int* __restrict__ seg,
                 unsigned short* __restrict__ xb0,
                 unsigned short* __restrict__ Wb0, unsigned short* __restrict__ Wb1,
                 unsigned short* __restrict__ Wfb,
                 int* __restrict__ hidx, int* __restrict__ t2s, int N)
{
    int t = blockIdx.x * 256 + threadIdx.x;
    int TA = 2 * (N + 1);
    unsigned short tmp[8];
    if (t < TA) {                         // xb0
        int n = t >> 1, h = t & 1;
        if (n < N) {
            const float* yr = vf + (size_t)n * 16 + h * 8;
#pragma unroll
            for (int j = 0; j < 8; ++j) tmp[j] = f2bf(yr[j]);
        } else {
#pragma unroll
            for (int j = 0; j < 8; ++j) tmp[j] = 0;
        }
        *(int4*)(xb0 + (size_t)n * 16 + h * 8) = *(int4*)tmp;
        return;
    }
    t -= TA;
    if (t < 2 * 14 * 64) {                // Wb0 / Wb1
        int w = t >= 896;
        int l = t - w * 896;
        int s = l >> 6, lane = l & 63;
        int q = lane >> 4, n = lane & 15;
        int tap = 2 * s + (q >> 1);
        int cb  = (q & 1) * 8;
        const float* W = w ? W1 : W0;
        unsigned short* Wb = w ? Wb1 : Wb0;
#pragma unroll
        for (int j = 0; j < 8; ++j)
            tmp[j] = (tap < 27) ? f2bf(W[((size_t)(tap * 16 + cb + j)) * 16 + n]) : 0;
        *(int4*)(Wb + (size_t)l * 8) = *(int4*)tmp;
        return;
    }
    t -= 2 * 14 * 64;
    if (t < 512) {                        // Wfb: B[k=q*8+j][ct*16+n], k>=16 -> 0
        int ct = t >> 6, lane = t & 63;
        int q = lane >> 4, n = lane & 15;
#pragma unroll
        for (int j = 0; j < 8; ++j)
            tmp[j] = (q < 2) ? f2bf(Wf[(size_t)(q * 8 + j) * 128 + ct * 16 + n]) : 0;
        *(int4*)(Wfb + (size_t)t * 8) = *(int4*)tmp;
        return;
    }
    t -= 512;
    if (t < N) { hidx[seg[t]] = t; return; }
    t -= N;
    if (t < N) {
        int s = seg[N + t];
        if (t == 0 || seg[N + t - 1] != s) t2s[s] = t;   // run leader
    }
}

// ---------------------------------------------------------------------------
// MFMA submanifold conv + per-block BN-stat partials (NO global atomics:
// plain stores to partials[block][32]; reduced by stats_reduce_kernel).
// Block = 64 voxels = 4 waves x 16. nbr slab staged via coalesced LDS loads.
// 14 steps of 16x16x32 bf16.
// ---------------------------------------------------------------------------
__global__ __launch_bounds__(256)
void conv_mfma_kernel(const unsigned short* __restrict__ xb,  // [(N+1),16] bf16
                      const unsigned short* __restrict__ Wb,  // [14*64*8] bf16
                      const int* __restrict__ nbr,            // [N,27]
                      float* __restrict__ y,                  // [N,16] pre-BN
                      float* __restrict__ partials,           // [nb,32]
                      int N)
{
    __shared__ int   sNbr[64 * 27];
    __shared__ float sred[32];
    int tid = threadIdx.x;
    if (tid < 32) sred[tid] = 0.f;

    int gb = blockIdx.x * 1728;           // 64*27
    int NT = N * 27;
#pragma unroll
    for (int i = 0; i < 7; ++i) {         // 7*256 = 1792 >= 1728
        int t = i * 256 + tid;
        if (t < 1728) {
            int g = gb + t;
            sNbr[t] = (g < NT) ? nbr[g] : -1;
        }
    }
    __syncthreads();

    int lane = tid & 63, wib = tid >> 6;
    int q = lane >> 4, m = lane & 15;
    int c0   = (q & 1) * 8;
    int tpar = q >> 1;
    int lvox = wib * 16 + m;
    int base = blockIdx.x * 64 + wib * 16;

    int idx[14];
#pragma unroll
    for (int s = 0; s < 14; ++s) {
        int tap = 2 * s + tpar;
        int id  = (tap < 27) ? sNbr[lvox * 27 + tap] : -1;
        idx[s]  = (id >= 0) ? id : N;     // row N = zeros
    }

    f32x4v acc = {0.f, 0.f, 0.f, 0.f};
#pragma unroll
    for (int s = 0; s < 14; ++s) {
        bfrag a = *(const bfrag*)(xb + (size_t)idx[s] * 16 + c0);
        bfrag b = *(const bfrag*)(Wb + ((size_t)s * 64 + lane) * 8);
        acc = __builtin_amdgcn_mfma_f32_16x16x32_bf16(a, b, acc, 0, 0, 0);
    }

    int o = lane & 15;
#pragma unroll
    for (int i = 0; i < 4; ++i) {
        int row = base + q * 4 + i;
        if (row < N) y[(size_t)row * 16 + o] = acc[i];
    }
    float s  = acc[0] + acc[1] + acc[2] + acc[3];
    float qq = acc[0] * acc[0] + acc[1] * acc[1] + acc[2] * acc[2] + acc[3] * acc[3];
    s  += __shfl_xor(s, 16);  s  += __shfl_xor(s, 32);
    qq += __shfl_xor(qq, 16); qq += __shfl_xor(qq, 32);
    if (lane < 16) {
        atomicAdd(&sred[lane], s);        // LDS atomics only (4 waves)
        atomicAdd(&sred[16 + lane], qq);
    }
    __syncthreads();
    if (tid < 32) partials[(size_t)blockIdx.x * 32 + tid] = sred[tid];
}

// ---------------------------------------------------------------------------
// Reduce partials [nb,32] -> stats [32]. One block, 256 threads = 32 ch x 8
// slices; coalesced 128B reads; LDS combine. No atomics anywhere.
// ---------------------------------------------------------------------------
__global__ __launch_bounds__(256)
void stats_reduce_kernel(const float* __restrict__ partials,
                         float* __restrict__ stats, int nb)
{
    __shared__ float red[8][32];
    int c = threadIdx.x & 31, sl = threadIdx.x >> 5;
    float s = 0.f;
    for (int i = sl; i < nb; i += 8)
        s += partials[(size_t)i * 32 + c];
    red[sl][c] = s;
    __syncthreads();
    if (threadIdx.x < 32) {
        float v = 0.f;
#pragma unroll
        for (int k = 0; k < 8; ++k) v += red[k][threadIdx.x];
        stats[threadIdx.x] = v;
    }
}

// ---------------------------------------------------------------------------
// xb1[n] = bf16(relu(y0[n]*sc+sh)), row N = zeros. Thread = 8 channels.
// ---------------------------------------------------------------------------
__global__ __launch_bounds__(256)
void bnrelu_cvt_kernel(const float* __restrict__ y0, const float* __restrict__ stats,
                       const float* __restrict__ g, const float* __restrict__ b,
                       float invN, unsigned short* __restrict__ xb, int N)
{
    int t = blockIdx.x * 256 + threadIdx.x;
    if (t >= (N + 1) * 2) return;
    int n = t >> 1, h = t & 1;
    unsigned short tmp[8];
    if (n < N) {
        const float* yr = y0 + (size_t)n * 16 + h * 8;
#pragma unroll
        for (int j = 0; j < 8; ++j) {
            int c = h * 8 + j;
            float mu  = stats[c] * invN;
            float var = stats[16 + c] * invN - mu * mu;
            float sc  = g[c] * rsqrtf(var + BN_EPS);
            float v   = fmaxf(fmaf(yr[j], sc, b[c] - mu * sc), 0.f);
            tmp[j] = f2bf(v);
        }
    } else {
#pragma unroll
        for (int j = 0; j < 8; ++j) tmp[j] = 0;
    }
    *(int4*)(xb + (size_t)n * 16 + h * 8) = *(int4*)tmp;
}

// ---------------------------------------------------------------------------
// Fused merge + final GEMM. Block = 64 output slots.
// Phase 1 (threads 0..127, thread = slot x half): merged row =
//   relu(bn1(y1[hidx[u]])) + (bobo + sum_{run} feat2[r] @ Wobo), fp32,
//   direct indices (no search); -> bf16 LDS tile.
// Phase 2 (4 waves): merged[64,16] @ Wf via mfma 16x16x32, +bf, store.
// ---------------------------------------------------------------------------
__global__ __launch_bounds__(256)
void merge_final_kernel(const float* __restrict__ y1, const float* __restrict__ stats,
                        const float* __restrict__ g, const float* __restrict__ b,
                        float invN,
                        const float* __restrict__ feat2, const float* __restrict__ Wobo,
                        const float* __restrict__ bobo,
                        const int* __restrict__ seg,
                        const int* __restrict__ hidx, const int* __restrict__ t2s,
                        const unsigned short* __restrict__ Wfb,
                        const float* __restrict__ bf,
                        float* __restrict__ out, int N, int U)
{
    __shared__ unsigned short smA[64 * 16];   // merged tile, bf16
    int tid = threadIdx.x;
    int u0  = blockIdx.x * 64;

    if (tid < 128) {
        int sl = tid >> 1, half = tid & 1;
        int u  = u0 + sl;
        float m[8];
#pragma unroll
        for (int j = 0; j < 8; ++j) m[j] = 0.f;
        if (u < U) {
            int hi = hidx[u];
            if ((unsigned)hi < (unsigned)N && seg[hi] == u) {
                const float4* yr = (const float4*)(y1 + (size_t)hi * 16 + half * 8);
                float4 v0 = yr[0], v1 = yr[1];
                float mv[8];
                *(float4*)(mv + 0) = v0; *(float4*)(mv + 4) = v1;
#pragma unroll
                for (int j = 0; j < 8; ++j) {
                    int c = half * 8 + j;
                    float mu  = stats[c] * invN;
                    float var = stats[16 + c] * invN - mu * mu;
                    float sc  = g[c] * rsqrtf(var + BN_EPS);
                    m[j] = fmaxf(fmaf(mv[j], sc, b[c] - mu * sc), 0.f);
                }
            }
            int r = t2s[u];
            if ((unsigned)r < (unsigned)N && seg[N + r] == u) {
                float a2[8];
#pragma unroll
                for (int j = 0; j < 8; ++j) a2[j] = bobo[half * 8 + j];
                do {
                    const float4* fr = (const float4*)(feat2 + (size_t)r * 16);
                    float4 f0 = fr[0], f1 = fr[1], f2 = fr[2], f3 = fr[3];
                    float fv[16];
                    *(float4*)(fv + 0)  = f0; *(float4*)(fv + 4)  = f1;
                    *(float4*)(fv + 8)  = f2; *(float4*)(fv + 12) = f3;
#pragma unroll
                    for (int c = 0; c < 16; ++c) {
                        float xc = fv[c];
                        const float* wr = Wobo + c * 16 + half * 8;  // uniform
#pragma unroll
                        for (int j = 0; j < 8; ++j) a2[j] = fmaf(xc, wr[j], a2[j]);
                    }
                    ++r;
                } while (r < N && seg[N + r] == u);
#pragma unroll
                for (int j = 0; j < 8; ++j) m[j] += a2[j];
            }
        }
        unsigned short tb[8];
#pragma unroll
        for (int j = 0; j < 8; ++j) tb[j] = f2bf(m[j]);
        *(int4*)(smA + (size_t)tid * 8) = *(int4*)tb;   // slot*16 + half*8
    }
    __syncthreads();

    int lane = tid & 63, w = tid >> 6;    // wave w = row-tile w
    int q = lane >> 4, n = lane & 15;
    bfrag a = {0, 0, 0, 0, 0, 0, 0, 0};
    if (q < 2)
        a = *(const bfrag*)(smA + ((size_t)(w * 16 + n) * 16 + q * 8));

#pragma unroll
    for (int ct = 0; ct < 8; ++ct) {
        bfrag bb = *(const bfrag*)(Wfb + ((size_t)(ct * 64 + lane)) * 8);
        f32x4v acc = {0.f, 0.f, 0.f, 0.f};
        acc = __builtin_amdgcn_mfma_f32_16x16x32_bf16(a, bb, acc, 0, 0, 0);
        int col = ct * 16 + n;
        float bv = bf[col];
#pragma unroll
        for (int i = 0; i < 4; ++i) {
            int u = u0 + w * 16 + q * 4 + i;
            if (u < U) out[(size_t)u * 128 + col] = acc[i] + bv;
        }
    }
}

extern "C" void kernel_launch(void* const* d_in, const int* in_sizes, int n_in,
                              void* d_out, int out_size, void* d_ws, size_t ws_size,
                              hipStream_t stream)
{
    const float* vf    = (const float*)d_in[0];
    const float* feat2 = (const float*)d_in[1];
    const float* W0    = (const float*)d_in[2];
    const float* g0    = (const float*)d_in[3];
    const float* b0    = (const float*)d_in[4];
    const float* W1    = (const float*)d_in[5];
    const float* g1    = (const float*)d_in[6];
    const float* b1    = (const float*)d_in[7];
    const float* Wobo  = (const float*)d_in[8];
    const float* bobo  = (const float*)d_in[9];
    const float* Wf    = (const float*)d_in[10];
    const float* bf    = (const float*)d_in[11];
    const int*   nbr   = (const int*)d_in[12];
    const int*   seg   = (const int*)d_in[13];

    int N = in_sizes[0] / 16;   // 100000
    int U = out_size / 128;     // num_segments

    float* out = (float*)d_out;
    float* ws  = (float*)d_ws;

    int gbConv = (N + 63) / 64;

    // Workspace (float units):
    float* y0    = ws;                                   // N*16
    float* y1    = y0 + (size_t)N * 16;                  // N*16
    float* stats = y1 + (size_t)N * 16;                  // 64 (stats0|stats1)
    float* part0 = stats + 64;                           // gbConv*32
    float* part1 = part0 + (size_t)gbConv * 32;          // gbConv*32
    unsigned short* xb0 = (unsigned short*)(part1 + (size_t)gbConv * 32);
    unsigned short* xb1 = xb0 + (size_t)(N + 1) * 16;    // (N+1)*16
    unsigned short* Wb0 = xb1 + (size_t)(N + 1) * 16;    // 14*64*8
    unsigned short* Wb1 = Wb0 + 14 * 64 * 8;             // 14*64*8
    unsigned short* Wfb = Wb1 + 14 * 64 * 8;             // 8*64*8
    int* hidx = (int*)(Wfb + 8 * 64 * 8);                // U
    int* t2s  = hidx + U;                                // U

    float invN  = 1.f / (float)N;
    int thrPrep = 2 * (N + 1) + 2 * 14 * 64 + 512 + 2 * N;
    int gbPrep  = (thrPrep + 255) / 256;
    int gbCvt   = ((N + 1) * 2 + 255) / 256;

    prep_kernel<<<gbPrep, 256, 0, stream>>>(vf, W0, W1, Wf, seg, xb0, Wb0, Wb1,
                                            Wfb, hidx, t2s, N);
    conv_mfma_kernel<<<gbConv, 256, 0, stream>>>(xb0, Wb0, nbr, y0, part0, N);
    stats_reduce_kernel<<<1, 256, 0, stream>>>(part0, stats, gbConv);
    bnrelu_cvt_kernel<<<gbCvt, 256, 0, stream>>>(y0, stats, g0, b0, invN, xb1, N);
    conv_mfma_kernel<<<gbConv, 256, 0, stream>>>(xb1, Wb1, nbr, y1, part1, N);
    stats_reduce_kernel<<<1, 256, 0, stream>>>(part1, stats + 32, gbConv);
    merge_final_kernel<<<(U + 63) / 64, 256, 0, stream>>>(y1, stats + 32, g1, b1, invN,
                                                          feat2, Wobo, bobo, seg,
                                                          hidx, t2s, Wfb, bf, out, N, U);
}

// Round 9
// 176.535 us; speedup vs baseline: 1.5101x; 1.5101x over previous
//
#include <hip/hip_runtime.h>

#define BN_EPS 1e-3f

using bfrag  = __attribute__((ext_vector_type(8))) short;  // 8 bf16 (4 VGPRs)
using f32x4v = __attribute__((ext_vector_type(4))) float;

__device__ __forceinline__ unsigned short f2bf(float f) {
    union { float f; unsigned u; } v; v.f = f;
    unsigned r = v.u + 0x7FFFu + ((v.u >> 16) & 1u);   // RNE
    return (unsigned short)(r >> 16);
}

// ---------------------------------------------------------------------------
// One prep kernel, thread ranges:
//  A: vf [N,16] fp32 -> xb0 [(N+1),16] bf16 (row N = zeros)
//  W: W0/W1 [27,16,16] -> Wb0/Wb1 MFMA B-frag order (14 K-steps)
//  F: Wf [16,128] -> Wfb B-frag order (8 col-tiles, K=16 padded to 32)
//  S: zero stats[64]
//  H: hidx[seg[r]] = r            (h contributor per slot; injective)
//  T: t2s[seg[N+r]] = r for run leaders (seg[N:2N] non-decreasing)
// Slots never written keep the 0xAA poison -> validity check in consumer.
// ---------------------------------------------------------------------------
__global__ __launch_bounds__(256)
void prep_kernel(const float* __restrict__ vf,
                 const float* __restrict__ W0, const float* __restrict__ W1,
                 const float* __restrict__ Wf, const int* __restrict__ seg,
                 unsigned short* __restrict__ xb0,
                 unsigned short* __restrict__ Wb0, unsigned short* __restrict__ Wb1,
                 unsigned short* __restrict__ Wfb,
                 float* __restrict__ stats,
                 int* __restrict__ hidx, int* __restrict__ t2s, int N)
{
    int t = blockIdx.x * 256 + threadIdx.x;
    int TA = 2 * (N + 1);
    unsigned short tmp[8];
    if (t < TA) {                         // xb0
        int n = t >> 1, h = t & 1;
        if (n < N) {
            const float* yr = vf + (size_t)n * 16 + h * 8;
#pragma unroll
            for (int j = 0; j < 8; ++j) tmp[j] = f2bf(yr[j]);
        } else {
#pragma unroll
            for (int j = 0; j < 8; ++j) tmp[j] = 0;
        }
        *(int4*)(xb0 + (size_t)n * 16 + h * 8) = *(int4*)tmp;
        return;
    }
    t -= TA;
    if (t < 2 * 14 * 64) {                // Wb0 / Wb1
        int w = t >= 896;
        int l = t - w * 896;
        int s = l >> 6, lane = l & 63;
        int q = lane >> 4, n = lane & 15;
        int tap = 2 * s + (q >> 1);
        int cb  = (q & 1) * 8;
        const float* W = w ? W1 : W0;
        unsigned short* Wb = w ? Wb1 : Wb0;
#pragma unroll
        for (int j = 0; j < 8; ++j)
            tmp[j] = (tap < 27) ? f2bf(W[((size_t)(tap * 16 + cb + j)) * 16 + n]) : 0;
        *(int4*)(Wb + (size_t)l * 8) = *(int4*)tmp;
        return;
    }
    t -= 2 * 14 * 64;
    if (t < 512) {                        // Wfb: B[k=q*8+j][ct*16+n], k>=16 -> 0
        int ct = t >> 6, lane = t & 63;
        int q = lane >> 4, n = lane & 15;
#pragma unroll
        for (int j = 0; j < 8; ++j)
            tmp[j] = (q < 2) ? f2bf(Wf[(size_t)(q * 8 + j) * 128 + ct * 16 + n]) : 0;
        *(int4*)(Wfb + (size_t)t * 8) = *(int4*)tmp;
        return;
    }
    t -= 512;
    if (t < 64) { stats[t] = 0.f; return; }   // zero BN stat accumulators
    t -= 64;
    if (t < N) { hidx[seg[t]] = t; return; }
    t -= N;
    if (t < N) {
        int s = seg[N + t];
        if (t == 0 || seg[N + t - 1] != s) t2s[s] = t;   // run leader
    }
}

// ---------------------------------------------------------------------------
// MFMA submanifold conv + per-block BN-stat partials (plain stores; no
// global atomics). Block = 64 voxels = 4 waves x 16. nbr slab staged via
// coalesced LDS loads. 14 steps of 16x16x32 bf16.
// ---------------------------------------------------------------------------
__global__ __launch_bounds__(256)
void conv_mfma_kernel(const unsigned short* __restrict__ xb,  // [(N+1),16] bf16
                      const unsigned short* __restrict__ Wb,  // [14*64*8] bf16
                      const int* __restrict__ nbr,            // [N,27]
                      float* __restrict__ y,                  // [N,16] pre-BN
                      float* __restrict__ partials,           // [nb,32]
                      int N)
{
    __shared__ int   sNbr[64 * 27];
    __shared__ float sred[32];
    int tid = threadIdx.x;
    if (tid < 32) sred[tid] = 0.f;

    int gb = blockIdx.x * 1728;           // 64*27
    int NT = N * 27;
#pragma unroll
    for (int i = 0; i < 7; ++i) {         // 7*256 = 1792 >= 1728
        int t = i * 256 + tid;
        if (t < 1728) {
            int g = gb + t;
            sNbr[t] = (g < NT) ? nbr[g] : -1;
        }
    }
    __syncthreads();

    int lane = tid & 63, wib = tid >> 6;
    int q = lane >> 4, m = lane & 15;
    int c0   = (q & 1) * 8;
    int tpar = q >> 1;
    int lvox = wib * 16 + m;
    int base = blockIdx.x * 64 + wib * 16;

    int idx[14];
#pragma unroll
    for (int s = 0; s < 14; ++s) {
        int tap = 2 * s + tpar;
        int id  = (tap < 27) ? sNbr[lvox * 27 + tap] : -1;
        idx[s]  = (id >= 0) ? id : N;     // row N = zeros
    }

    f32x4v acc = {0.f, 0.f, 0.f, 0.f};
#pragma unroll
    for (int s = 0; s < 14; ++s) {
        bfrag a = *(const bfrag*)(xb + (size_t)idx[s] * 16 + c0);
        bfrag b = *(const bfrag*)(Wb + ((size_t)s * 64 + lane) * 8);
        acc = __builtin_amdgcn_mfma_f32_16x16x32_bf16(a, b, acc, 0, 0, 0);
    }

    int o = lane & 15;
#pragma unroll
    for (int i = 0; i < 4; ++i) {
        int row = base + q * 4 + i;
        if (row < N) y[(size_t)row * 16 + o] = acc[i];
    }
    float s  = acc[0] + acc[1] + acc[2] + acc[3];
    float qq = acc[0] * acc[0] + acc[1] * acc[1] + acc[2] * acc[2] + acc[3] * acc[3];
    s  += __shfl_xor(s, 16);  s  += __shfl_xor(s, 32);
    qq += __shfl_xor(qq, 16); qq += __shfl_xor(qq, 32);
    if (lane < 16) {
        atomicAdd(&sred[lane], s);        // LDS atomics only (4 waves)
        atomicAdd(&sred[16 + lane], qq);
    }
    __syncthreads();
    if (tid < 32) partials[(size_t)blockIdx.x * 32 + tid] = sred[tid];
}

// ---------------------------------------------------------------------------
// Reduce partials [nb,32] -> stats [32] (stats pre-zeroed by prep).
// 32 blocks x 256 threads: thread = (slice, channel); coalesced 128B row
// reads, ~6 independent loads/thread; LDS combine; 32 atomics/block
// (32 same-address atomics TOTAL per channel across the grid).
// ---------------------------------------------------------------------------
__global__ __launch_bounds__(256)
void stats_reduce_kernel(const float* __restrict__ partials,
                         float* __restrict__ stats, int nb)
{
    __shared__ float red[8][32];
    int c = threadIdx.x & 31, sl = threadIdx.x >> 5;
    float s = 0.f;
    for (int i = blockIdx.x * 8 + sl; i < nb; i += gridDim.x * 8)
        s += partials[(size_t)i * 32 + c];
    red[sl][c] = s;
    __syncthreads();
    if (threadIdx.x < 32) {
        float v = 0.f;
#pragma unroll
        for (int k = 0; k < 8; ++k) v += red[k][threadIdx.x];
        atomicAdd(&stats[threadIdx.x], v);
    }
}

// ---------------------------------------------------------------------------
// xb1[n] = bf16(relu(y0[n]*sc+sh)), row N = zeros. Thread = 8 channels.
// ---------------------------------------------------------------------------
__global__ __launch_bounds__(256)
void bnrelu_cvt_kernel(const float* __restrict__ y0, const float* __restrict__ stats,
                       const float* __restrict__ g, const float* __restrict__ b,
                       float invN, unsigned short* __restrict__ xb, int N)
{
    int t = blockIdx.x * 256 + threadIdx.x;
    if (t >= (N + 1) * 2) return;
    int n = t >> 1, h = t & 1;
    unsigned short tmp[8];
    if (n < N) {
        const float* yr = y0 + (size_t)n * 16 + h * 8;
#pragma unroll
        for (int j = 0; j < 8; ++j) {
            int c = h * 8 + j;
            float mu  = stats[c] * invN;
            float var = stats[16 + c] * invN - mu * mu;
            float sc  = g[c] * rsqrtf(var + BN_EPS);
            float v   = fmaxf(fmaf(yr[j], sc, b[c] - mu * sc), 0.f);
            tmp[j] = f2bf(v);
        }
    } else {
#pragma unroll
        for (int j = 0; j < 8; ++j) tmp[j] = 0;
    }
    *(int4*)(xb + (size_t)n * 16 + h * 8) = *(int4*)tmp;
}

// ---------------------------------------------------------------------------
// Fused merge + final GEMM. Block = 64 output slots.
// Phase 1 (threads 0..127, thread = slot x half): merged row =
//   relu(bn1(y1[hidx[u]])) + (bobo + sum_{run} feat2[r] @ Wobo), fp32,
//   direct indices (no search); -> bf16 LDS tile.
// Phase 2 (4 waves): merged[64,16] @ Wf via mfma 16x16x32, +bf, store.
// ---------------------------------------------------------------------------
__global__ __launch_bounds__(256)
void merge_final_kernel(const float* __restrict__ y1, const float* __restrict__ stats,
                        const float* __restrict__ g, const float* __restrict__ b,
                        float invN,
                        const float* __restrict__ feat2, const float* __restrict__ Wobo,
                        const float* __restrict__ bobo,
                        const int* __restrict__ seg,
                        const int* __restrict__ hidx, const int* __restrict__ t2s,
                        const unsigned short* __restrict__ Wfb,
                        const float* __restrict__ bf,
                        float* __restrict__ out, int N, int U)
{
    __shared__ unsigned short smA[64 * 16];   // merged tile, bf16
    int tid = threadIdx.x;
    int u0  = blockIdx.x * 64;

    if (tid < 128) {
        int sl = tid >> 1, half = tid & 1;
        int u  = u0 + sl;
        float m[8];
#pragma unroll
        for (int j = 0; j < 8; ++j) m[j] = 0.f;
        if (u < U) {
            int hi = hidx[u];
            if ((unsigned)hi < (unsigned)N && seg[hi] == u) {
                const float4* yr = (const float4*)(y1 + (size_t)hi * 16 + half * 8);
                float4 v0 = yr[0], v1 = yr[1];
                float mv[8];
                *(float4*)(mv + 0) = v0; *(float4*)(mv + 4) = v1;
#pragma unroll
                for (int j = 0; j < 8; ++j) {
                    int c = half * 8 + j;
                    float mu  = stats[c] * invN;
                    float var = stats[16 + c] * invN - mu * mu;
                    float sc  = g[c] * rsqrtf(var + BN_EPS);
                    m[j] = fmaxf(fmaf(mv[j], sc, b[c] - mu * sc), 0.f);
                }
            }
            int r = t2s[u];
            if ((unsigned)r < (unsigned)N && seg[N + r] == u) {
                float a2[8];
#pragma unroll
                for (int j = 0; j < 8; ++j) a2[j] = bobo[half * 8 + j];
                do {
                    const float4* fr = (const float4*)(feat2 + (size_t)r * 16);
                    float4 f0 = fr[0], f1 = fr[1], f2 = fr[2], f3 = fr[3];
                    float fv[16];
                    *(float4*)(fv + 0)  = f0; *(float4*)(fv + 4)  = f1;
                    *(float4*)(fv + 8)  = f2; *(float4*)(fv + 12) = f3;
#pragma unroll
                    for (int c = 0; c < 16; ++c) {
                        float xc = fv[c];
                        const float* wr = Wobo + c * 16 + half * 8;  // uniform
#pragma unroll
                        for (int j = 0; j < 8; ++j) a2[j] = fmaf(xc, wr[j], a2[j]);
                    }
                    ++r;
                } while (r < N && seg[N + r] == u);
#pragma unroll
                for (int j = 0; j < 8; ++j) m[j] += a2[j];
            }
        }
        unsigned short tb[8];
#pragma unroll
        for (int j = 0; j < 8; ++j) tb[j] = f2bf(m[j]);
        *(int4*)(smA + (size_t)tid * 8) = *(int4*)tb;   // slot*16 + half*8
    }
    __syncthreads();

    int lane = tid & 63, w = tid >> 6;    // wave w = row-tile w
    int q = lane >> 4, n = lane & 15;
    bfrag a = {0, 0, 0, 0, 0, 0, 0, 0};
    if (q < 2)
        a = *(const bfrag*)(smA + ((size_t)(w * 16 + n) * 16 + q * 8));

#pragma unroll
    for (int ct = 0; ct < 8; ++ct) {
        bfrag bb = *(const bfrag*)(Wfb + ((size_t)(ct * 64 + lane)) * 8);
        f32x4v acc = {0.f, 0.f, 0.f, 0.f};
        acc = __builtin_amdgcn_mfma_f32_16x16x32_bf16(a, bb, acc, 0, 0, 0);
        int col = ct * 16 + n;
        float bv = bf[col];
#pragma unroll
        for (int i = 0; i < 4; ++i) {
            int u = u0 + w * 16 + q * 4 + i;
            if (u < U) out[(size_t)u * 128 + col] = acc[i] + bv;
        }
    }
}

extern "C" void kernel_launch(void* const* d_in, const int* in_sizes, int n_in,
                              void* d_out, int out_size, void* d_ws, size_t ws_size,
                              hipStream_t stream)
{
    const float* vf    = (const float*)d_in[0];
    const float* feat2 = (const float*)d_in[1];
    const float* W0    = (const float*)d_in[2];
    const float* g0    = (const float*)d_in[3];
    const float* b0    = (const float*)d_in[4];
    const float* W1    = (const float*)d_in[5];
    const float* g1    = (const float*)d_in[6];
    const float* b1    = (const float*)d_in[7];
    const float* Wobo  = (const float*)d_in[8];
    const float* bobo  = (const float*)d_in[9];
    const float* Wf    = (const float*)d_in[10];
    const float* bf    = (const float*)d_in[11];
    const int*   nbr   = (const int*)d_in[12];
    const int*   seg   = (const int*)d_in[13];

    int N = in_sizes[0] / 16;   // 100000
    int U = out_size / 128;     // num_segments

    float* out = (float*)d_out;
    float* ws  = (float*)d_ws;

    int gbConv = (N + 63) / 64;

    // Workspace (float units):
    float* y0    = ws;                                   // N*16
    float* y1    = y0 + (size_t)N * 16;                  // N*16
    float* stats = y1 + (size_t)N * 16;                  // 64 (stats0|stats1)
    float* part0 = stats + 64;                           // gbConv*32
    float* part1 = part0 + (size_t)gbConv * 32;          // gbConv*32
    unsigned short* xb0 = (unsigned short*)(part1 + (size_t)gbConv * 32);
    unsigned short* xb1 = xb0 + (size_t)(N + 1) * 16;    // (N+1)*16
    unsigned short* Wb0 = xb1 + (size_t)(N + 1) * 16;    // 14*64*8
    unsigned short* Wb1 = Wb0 + 14 * 64 * 8;             // 14*64*8
    unsigned short* Wfb = Wb1 + 14 * 64 * 8;             // 8*64*8
    int* hidx = (int*)(Wfb + 8 * 64 * 8);                // U
    int* t2s  = hidx + U;                                // U

    float invN  = 1.f / (float)N;
    int thrPrep = 2 * (N + 1) + 2 * 14 * 64 + 512 + 64 + 2 * N;
    int gbPrep  = (thrPrep + 255) / 256;
    int gbCvt   = ((N + 1) * 2 + 255) / 256;

    prep_kernel<<<gbPrep, 256, 0, stream>>>(vf, W0, W1, Wf, seg, xb0, Wb0, Wb1,
                                            Wfb, stats, hidx, t2s, N);
    conv_mfma_kernel<<<gbConv, 256, 0, stream>>>(xb0, Wb0, nbr, y0, part0, N);
    stats_reduce_kernel<<<32, 256, 0, stream>>>(part0, stats, gbConv);
    bnrelu_cvt_kernel<<<gbCvt, 256, 0, stream>>>(y0, stats, g0, b0, invN, xb1, N);
    conv_mfma_kernel<<<gbConv, 256, 0, stream>>>(xb1, Wb1, nbr, y1, part1, N);
    stats_reduce_kernel<<<32, 256, 0, stream>>>(part1, stats + 32, gbConv);
    merge_final_kernel<<<(U + 63) / 64, 256, 0, stream>>>(y1, stats + 32, g1, b1, invN,
                                                          feat2, Wobo, bobo, seg,
                                                          hidx, t2s, Wfb, bf, out, N, U);
}